// Round 1
// baseline (1303.050 us; speedup 1.0000x reference)
//
#include <hip/hip_runtime.h>
#include <math.h>

#define B_ 16
#define D_ 256
#define M_ 2048
#define N_ 2048
#define EPSF 1e-8f
#define AVAL (1.0f/2048.0f)   // a_i = 1/M = b_j = 1/N ; m = min(sum a, sum b) = 1

__device__ __forceinline__ float wredsum(float x){
  #pragma unroll
  for (int off=32; off; off>>=1) x += __shfl_xor(x, off);
  return x;
}
__device__ __forceinline__ float wredmax(float x){
  #pragma unroll
  for (int off=32; off; off>>=1) x = fmaxf(x, __shfl_xor(x, off));
  return x;
}

// ---------------- S[b,m,n] = (1/16) * sum_d A[b,d,m]*Bt[b,d,n] ----------------
__global__ __launch_bounds__(256) void gemm_kernel(const float* __restrict__ A,
                                                   const float* __restrict__ Bt,
                                                   float* __restrict__ S)
{
  __shared__ float As[16][128];
  __shared__ float Bs[16][128];
  const int b  = blockIdx.z;
  const int m0 = blockIdx.y * 128;
  const int n0 = blockIdx.x * 128;
  const int t  = threadIdx.x;
  const int tx = t & 15, ty = t >> 4;

  float acc[8][8];
  #pragma unroll
  for (int r=0;r<8;r++)
    #pragma unroll
    for (int c=0;c<8;c++) acc[r][c]=0.0f;

  const size_t baseA = (size_t)b * D_ * M_;
  for (int kc=0; kc<D_; kc+=16){
    #pragma unroll
    for (int i=0;i<2;i++){
      int L = t + i*256;
      int d = L >> 5;
      int mq = (L & 31) * 4;
      *(float4*)&As[d][mq] = *(const float4*)&A [baseA + (size_t)(kc+d)*M_ + m0 + mq];
      *(float4*)&Bs[d][mq] = *(const float4*)&Bt[baseA + (size_t)(kc+d)*N_ + n0 + mq];
    }
    __syncthreads();
    #pragma unroll
    for (int kk=0;kk<16;kk++){
      float ar[8], br[8];
      *(float4*)&ar[0] = *(const float4*)&As[kk][ty*8];
      *(float4*)&ar[4] = *(const float4*)&As[kk][ty*8+4];
      *(float4*)&br[0] = *(const float4*)&Bs[kk][tx*8];
      *(float4*)&br[4] = *(const float4*)&Bs[kk][tx*8+4];
      #pragma unroll
      for (int r=0;r<8;r++)
        #pragma unroll
        for (int c=0;c<8;c++)
          acc[r][c] = fmaf(ar[r], br[c], acc[r][c]);
    }
    __syncthreads();
  }
  const float sc = 0.0625f;  // 1/sqrt(256)
  #pragma unroll
  for (int r=0;r<8;r++){
    size_t o = ((size_t)b*M_ + (size_t)(m0 + ty*8 + r)) * N_ + n0 + tx*8;
    float4 w0 = make_float4(acc[r][0]*sc, acc[r][1]*sc, acc[r][2]*sc, acc[r][3]*sc);
    float4 w1 = make_float4(acc[r][4]*sc, acc[r][5]*sc, acc[r][6]*sc, acc[r][7]*sc);
    *(float4*)&S[o]   = w0;
    *(float4*)&S[o+4] = w1;
  }
}

// ---------------- per-row: lse and Khat row sum (y0) ----------------
__global__ __launch_bounds__(256) void stats_kernel(const float* __restrict__ S,
                                                    const float* __restrict__ rho,
                                                    float* __restrict__ lse,
                                                    float* __restrict__ y0)
{
  const int b = blockIdx.y;
  const int m = blockIdx.x*4 + (threadIdx.x>>6);
  const int lane = threadIdx.x & 63;
  const float invrho = 1.0f / fmaxf(rho[0], EPSF);
  const float4* row = (const float4*)(S + ((size_t)b*M_ + m)*N_);
  float4 vals[8];
  float mx = -3.4e38f;
  #pragma unroll
  for (int k=0;k<8;k++){
    float4 v = row[lane + 64*k];
    vals[k] = v;
    mx = fmaxf(mx, fmaxf(fmaxf(v.x,v.y), fmaxf(v.z,v.w)));
  }
  mx = wredmax(mx);
  float e1=0.0f, e2=0.0f;
  #pragma unroll
  for (int k=0;k<8;k++){
    float4 v = vals[k];
    e1 += __expf(v.x-mx)+__expf(v.y-mx)+__expf(v.z-mx)+__expf(v.w-mx);
    e2 += __expf((v.x-mx)*invrho)+__expf((v.y-mx)*invrho)
        + __expf((v.z-mx)*invrho)+__expf((v.w-mx)*invrho);
  }
  e1 = wredsum(e1); e2 = wredsum(e2);
  if (lane==0){
    float lg = __logf(e1);
    lse[b*M_+m] = mx + lg;
    y0 [b*M_+m] = e2 * __expf(-lg*invrho);   // sum_j exp((s-lse)/rho)
  }
}

// ---------------- g0 = 1/max(sum Khat, eps); u = r1; v=1; w=0 ----------------
__global__ __launch_bounds__(256) void init_kernel(const float* __restrict__ y0,
                                                   float* __restrict__ u, float* __restrict__ v,
                                                   float* __restrict__ w, float* __restrict__ g)
{
  const int b = blockIdx.x; const int t = threadIdx.x;
  float s = 0.0f;
  for (int i=t;i<M_;i+=256) s += y0[b*M_+i];
  s = wredsum(s);
  __shared__ float red[4];
  __shared__ float gsh;
  if ((t&63)==0) red[t>>6]=s;
  __syncthreads();
  if (t==0){
    float tot = red[0]+red[1]+red[2]+red[3];
    float gg = 1.0f / fmaxf(tot, EPSF);
    g[b]=gg; gsh=gg;
  }
  __syncthreads();
  float gg = gsh;
  for (int i=t;i<M_;i+=256){
    float rs = gg * y0[b*M_+i];                 // rowsum with u=v=1
    float r  = fminf(AVAL / fmaxf(rs, EPSF), 1.0f);
    u[b*M_+i] = r;
    v[b*M_+i] = 1.0f;
    w[b*M_+i] = 0.0f;
  }
}

// ---------------- y_i = (Khat v)_i ; u_i *= min(a/max(g u_i y_i,eps),1) ----------------
__global__ __launch_bounds__(256) void row_kernel(const float* __restrict__ S,
                                                  const float* __restrict__ lse,
                                                  const float* __restrict__ vv,
                                                  float* __restrict__ u,
                                                  const float* __restrict__ g,
                                                  const float* __restrict__ rho)
{
  const int b = blockIdx.y;
  const int m = blockIdx.x*4 + (threadIdx.x>>6);
  const int lane = threadIdx.x & 63;
  const float invrho = 1.0f / fmaxf(rho[0], EPSF);
  const float l = lse[b*M_+m];
  const float4* row = (const float4*)(S + ((size_t)b*M_ + m)*N_);
  const float4* vp  = (const float4*)(vv + b*N_);
  float acc=0.0f;
  #pragma unroll
  for (int k=0;k<8;k++){
    float4 s4 = row[lane+64*k];
    float4 v4 = vp [lane+64*k];
    acc += __expf((s4.x-l)*invrho)*v4.x + __expf((s4.y-l)*invrho)*v4.y
         + __expf((s4.z-l)*invrho)*v4.z + __expf((s4.w-l)*invrho)*v4.w;
  }
  acc = wredsum(acc);
  if (lane==0){
    float gg = g[b];
    float ui = u[b*M_+m];
    float rs = gg*ui*acc;
    float r  = fminf(AVAL / fmaxf(rs, EPSF), 1.0f);
    u[b*M_+m] = ui*r;
  }
}

// ---------------- w_j += sum_i u_i Khat_ij (partial over 64-row chunks) ----------------
__global__ __launch_bounds__(256) void col_kernel(const float* __restrict__ S,
                                                  const float* __restrict__ lse,
                                                  const float* __restrict__ u,
                                                  float* __restrict__ w,
                                                  const float* __restrict__ rho)
{
  const int b  = blockIdx.y;
  const int i0 = blockIdx.x*64;
  const int t  = threadIdx.x;
  const int j0 = t*8;
  const float invrho = 1.0f/fmaxf(rho[0],EPSF);
  float acc[8];
  #pragma unroll
  for (int k=0;k<8;k++) acc[k]=0.0f;
  for (int i=0;i<64;i++){
    int r = i0+i;
    float l  = lse[b*M_+r];
    float ui = u  [b*M_+r];
    const float* sr = S + ((size_t)b*M_ + r)*N_ + j0;
    float4 a4 = *(const float4*)sr;
    float4 b4 = *(const float4*)(sr+4);
    acc[0] += ui*__expf((a4.x-l)*invrho);
    acc[1] += ui*__expf((a4.y-l)*invrho);
    acc[2] += ui*__expf((a4.z-l)*invrho);
    acc[3] += ui*__expf((a4.w-l)*invrho);
    acc[4] += ui*__expf((b4.x-l)*invrho);
    acc[5] += ui*__expf((b4.y-l)*invrho);
    acc[6] += ui*__expf((b4.z-l)*invrho);
    acc[7] += ui*__expf((b4.w-l)*invrho);
  }
  #pragma unroll
  for (int k=0;k<8;k++) atomicAdd(&w[b*N_+j0+k], acc[k]);
}

// ---------------- v_j *= c_j ; g *= 1/max(g*sum(w v),eps) ; zero w ----------------
__global__ __launch_bounds__(256) void vupd_kernel(float* __restrict__ w,
                                                   float* __restrict__ v,
                                                   float* __restrict__ g)
{
  const int b = blockIdx.x; const int t = threadIdx.x;
  const float gg = g[b];
  float part = 0.0f;
  for (int i=t;i<N_;i+=256){
    float wj = w[b*N_+i];
    float vj = v[b*N_+i];
    float cs = gg*vj*wj;
    float c  = fminf(AVAL/fmaxf(cs,EPSF), 1.0f);
    vj *= c;
    v[b*N_+i]=vj;
    part += wj*vj;
    w[b*N_+i]=0.0f;
  }
  part = wredsum(part);
  __shared__ float red[4];
  if ((t&63)==0) red[t>>6]=part;
  __syncthreads();
  if (t==0){
    float ssum = red[0]+red[1]+red[2]+red[3];
    float tot  = gg*ssum;
    g[b] = gg / fmaxf(tot, EPSF);
  }
}

// ---------------- matches written in place over S; fused rowsum + matches@t^T ----------------
__global__ __launch_bounds__(256) void final_kernel(float* __restrict__ S,
                                                    const float* __restrict__ lse,
                                                    const float* __restrict__ u,
                                                    const float* __restrict__ v,
                                                    const float* __restrict__ g,
                                                    const float* __restrict__ tgt,
                                                    const float* __restrict__ rho,
                                                    float* __restrict__ rowsum,
                                                    float* __restrict__ wref)
{
  const int b = blockIdx.y;
  const int m = blockIdx.x*4 + (threadIdx.x>>6);
  const int lane = threadIdx.x & 63;
  const float invrho = 1.0f/fmaxf(rho[0],EPSF);
  const float l  = lse[b*M_+m];
  const float gu = g[b]*u[b*M_+m];
  float4* row = (float4*)(S + ((size_t)b*M_ + m)*N_);
  const float4* vp = (const float4*)(v + (size_t)b*N_);
  const float4* t0 = (const float4*)(tgt + ((size_t)b*3+0)*N_);
  const float4* t1 = (const float4*)(tgt + ((size_t)b*3+1)*N_);
  const float4* t2 = (const float4*)(tgt + ((size_t)b*3+2)*N_);
  float rs=0.0f, a0=0.0f, a1=0.0f, a2=0.0f;
  #pragma unroll
  for (int k=0;k<8;k++){
    int off = lane + 64*k;
    float4 s4 = row[off];
    float4 v4 = vp [off];
    float4 q0 = t0[off], q1 = t1[off], q2 = t2[off];
    float m0v = gu*__expf((s4.x-l)*invrho)*v4.x;
    float m1v = gu*__expf((s4.y-l)*invrho)*v4.y;
    float m2v = gu*__expf((s4.z-l)*invrho)*v4.z;
    float m3v = gu*__expf((s4.w-l)*invrho)*v4.w;
    rs += m0v+m1v+m2v+m3v;
    a0 += m0v*q0.x + m1v*q0.y + m2v*q0.z + m3v*q0.w;
    a1 += m0v*q1.x + m1v*q1.y + m2v*q1.z + m3v*q1.w;
    a2 += m0v*q2.x + m1v*q2.y + m2v*q2.z + m3v*q2.w;
    row[off] = make_float4(m0v,m1v,m2v,m3v);
  }
  rs = wredsum(rs); a0=wredsum(a0); a1=wredsum(a1); a2=wredsum(a2);
  if (lane==0){
    rowsum[b*M_+m] = rs;
    float inv = 1.0f/(rs+1e-6f);
    size_t o = ((size_t)b*M_+m)*3;
    wref[o]=a0*inv; wref[o+1]=a1*inv; wref[o+2]=a2*inv;
  }
}

// ---------------- 3x3 Kabsch: SVD via Jacobi on cov^T cov ----------------
__device__ __forceinline__ void mat3_svd_rot(const float cov[3][3], float R[3][3])
{
  float mx = 1e-30f;
  for (int p=0;p<3;p++) for (int q=0;q<3;q++) mx = fmaxf(mx, fabsf(cov[p][q]));
  const float inv = 1.0f/mx;
  float Cm[3][3];
  for (int p=0;p<3;p++) for (int q=0;q<3;q++) Cm[p][q]=cov[p][q]*inv;

  float G[3][3];
  for (int p=0;p<3;p++)
    for (int q=0;q<3;q++)
      G[p][q] = Cm[0][p]*Cm[0][q] + Cm[1][p]*Cm[1][q] + Cm[2][p]*Cm[2][q];
  float V[3][3] = {{1,0,0},{0,1,0},{0,0,1}};
  const int PP[3]={0,0,1}, QQ[3]={1,2,2};
  for (int sweep=0;sweep<12;sweep++){
    for (int r=0;r<3;r++){
      int p=PP[r], q=QQ[r];
      float apq = G[p][q];
      if (fabsf(apq) < 1e-20f) continue;
      float tau = (G[q][q]-G[p][p])/(2.0f*apq);
      float tt  = (tau>=0.0f?1.0f:-1.0f)/(fabsf(tau)+sqrtf(1.0f+tau*tau));
      float cc  = 1.0f/sqrtf(1.0f+tt*tt);
      float ss  = tt*cc;
      for (int k=0;k<3;k++){ float gkp=G[k][p], gkq=G[k][q]; G[k][p]=cc*gkp-ss*gkq; G[k][q]=ss*gkp+cc*gkq; }
      for (int k=0;k<3;k++){ float gpk=G[p][k], gqk=G[q][k]; G[p][k]=cc*gpk-ss*gqk; G[q][k]=ss*gpk+cc*gqk; }
      for (int k=0;k<3;k++){ float vkp=V[k][p], vkq=V[k][q]; V[k][p]=cc*vkp-ss*vkq; V[k][q]=ss*vkp+cc*vkq; }
    }
  }
  float ev[3]={G[0][0],G[1][1],G[2][2]};
  int i0=0,i1=1,i2=2,tmp;
  if (ev[i0]<ev[i1]){tmp=i0;i0=i1;i1=tmp;}
  if (ev[i0]<ev[i2]){tmp=i0;i0=i2;i2=tmp;}
  if (ev[i1]<ev[i2]){tmp=i1;i1=i2;i2=tmp;}
  const int idx[3]={i0,i1,i2};
  float Vs[3][3];
  for (int k=0;k<3;k++) for (int i=0;i<3;i++) Vs[i][k]=V[i][idx[k]];
  float U[3][3]; float nrm[3];
  for (int k=0;k<3;k++){
    float ux = Cm[0][0]*Vs[0][k]+Cm[0][1]*Vs[1][k]+Cm[0][2]*Vs[2][k];
    float uy = Cm[1][0]*Vs[0][k]+Cm[1][1]*Vs[1][k]+Cm[1][2]*Vs[2][k];
    float uz = Cm[2][0]*Vs[0][k]+Cm[2][1]*Vs[1][k]+Cm[2][2]*Vs[2][k];
    float n = sqrtf(ux*ux+uy*uy+uz*uz);
    nrm[k]=n;
    float in = (n>1e-20f)?1.0f/n:0.0f;
    U[0][k]=ux*in; U[1][k]=uy*in; U[2][k]=uz*in;
  }
  if (nrm[2] < 1e-6f*fmaxf(nrm[0],1e-20f)){  // degenerate smallest sv: complete basis
    U[0][2]=U[1][0]*U[2][1]-U[2][0]*U[1][1];
    U[1][2]=U[2][0]*U[0][1]-U[0][0]*U[2][1];
    U[2][2]=U[0][0]*U[1][1]-U[1][0]*U[0][1];
  }
  float detC = Cm[0][0]*(Cm[1][1]*Cm[2][2]-Cm[1][2]*Cm[2][1])
             - Cm[0][1]*(Cm[1][0]*Cm[2][2]-Cm[1][2]*Cm[2][0])
             + Cm[0][2]*(Cm[1][0]*Cm[2][1]-Cm[1][1]*Cm[2][0]);
  float d2 = (detC>0.0f)?1.0f:-1.0f;
  for (int p=0;p<3;p++)
    for (int q=0;q<3;q++)
      R[p][q] = Vs[p][0]*U[q][0] + Vs[p][1]*U[q][1] + d2*Vs[p][2]*U[q][2];
}

__global__ __launch_bounds__(256) void rigid_kernel(const float* __restrict__ src,
                                                    const float* __restrict__ wref,
                                                    const float* __restrict__ rowsum,
                                                    float* __restrict__ out)
{
  const int b = blockIdx.x; const int t = threadIdx.x;
  float acc[16];
  #pragma unroll
  for (int k=0;k<16;k++) acc[k]=0.0f;
  for (int i=t;i<M_;i+=256){
    float wgt = rowsum[b*M_+i];
    float ax = src[((size_t)b*3+0)*M_+i];
    float ay = src[((size_t)b*3+1)*M_+i];
    float az = src[((size_t)b*3+2)*M_+i];
    const float* wr = wref + ((size_t)b*M_+i)*3;
    float bx=wr[0], by=wr[1], bz=wr[2];
    acc[0]+=wgt;
    acc[1]+=wgt*ax; acc[2]+=wgt*ay; acc[3]+=wgt*az;
    acc[4]+=wgt*bx; acc[5]+=wgt*by; acc[6]+=wgt*bz;
    acc[7] +=wgt*ax*bx; acc[8] +=wgt*ax*by; acc[9] +=wgt*ax*bz;
    acc[10]+=wgt*ay*bx; acc[11]+=wgt*ay*by; acc[12]+=wgt*ay*bz;
    acc[13]+=wgt*az*bx; acc[14]+=wgt*az*by; acc[15]+=wgt*az*bz;
  }
  __shared__ float red[4][16];
  const int wid = t>>6, lane = t&63;
  #pragma unroll
  for (int k=0;k<16;k++){
    float v = acc[k];
    #pragma unroll
    for (int off=32; off; off>>=1) v += __shfl_xor(v, off);
    if (lane==0) red[wid][k]=v;
  }
  __syncthreads();
  if (t==0){
    float s[16];
    #pragma unroll
    for (int k=0;k<16;k++) s[k]=red[0][k]+red[1][k]+red[2][k]+red[3][k];
    float wsum = s[0];
    float denom = wsum + 1e-6f;
    float ca[3]={s[1]/denom, s[2]/denom, s[3]/denom};
    float cb[3]={s[4]/denom, s[5]/denom, s[6]/denom};
    float sw = wsum/denom;
    float cov[3][3];
    for (int p=0;p<3;p++)
      for (int q=0;q<3;q++)
        cov[p][q] = s[7+p*3+q]/denom + (sw-2.0f)*ca[p]*cb[q];
    float R[3][3];
    mat3_svd_rot(cov, R);
    float tr[3];
    for (int p=0;p<3;p++)
      tr[p] = -(R[p][0]*ca[0]+R[p][1]*ca[1]+R[p][2]*ca[2]) + cb[p];
    for (int p=0;p<3;p++)
      for (int q=0;q<3;q++)
        out[b*9 + p*3 + q] = R[p][q];
    for (int p=0;p<3;p++)
      out[144 + b*3 + p] = tr[p];
  }
}

extern "C" void kernel_launch(void* const* d_in, const int* in_sizes, int n_in,
                              void* d_out, int out_size, void* d_ws, size_t ws_size,
                              hipStream_t stream)
{
  const float* se  = (const float*)d_in[0];
  const float* te  = (const float*)d_in[1];
  const float* src = (const float*)d_in[2];
  const float* tgt = (const float*)d_in[3];
  const float* rho = (const float*)d_in[4];
  float* out = (float*)d_out;
  float* S   = out + 192;                 // match_mats region doubles as scratch
  float* ws  = (float*)d_ws;
  float* lse = ws;                        // 16*2048
  float* y0  = ws + 32768;                // 16*2048 (also final rowsum)
  float* u   = ws + 65536;                // 16*2048
  float* v   = ws + 98304;                // 16*2048
  float* w   = ws + 131072;               // 16*2048
  float* g   = ws + 163840;               // 16
  float* wref= ws + 163904;               // 16*2048*3

  gemm_kernel <<<dim3(16,16,16),256,0,stream>>>(se,te,S);
  stats_kernel<<<dim3(512,16),  256,0,stream>>>(S,rho,lse,y0);
  init_kernel <<<dim3(16),      256,0,stream>>>(y0,u,v,w,g);
  for (int it=0; it<5; ++it){
    if (it>0) row_kernel<<<dim3(512,16),256,0,stream>>>(S,lse,v,u,g,rho);
    col_kernel <<<dim3(32,16),256,0,stream>>>(S,lse,u,w,rho);
    vupd_kernel<<<dim3(16),   256,0,stream>>>(w,v,g);
  }
  final_kernel<<<dim3(512,16),256,0,stream>>>(S,lse,u,v,g,tgt,rho,y0,wref);
  rigid_kernel<<<dim3(16),    256,0,stream>>>(src,wref,y0,out);
}

// Round 3
// 962.586 us; speedup vs baseline: 1.3537x; 1.3537x over previous
//
#include <hip/hip_runtime.h>
#include <math.h>

#define B_ 16
#define D_ 256
#define M_ 2048
#define N_ 2048
#define EPSF 1e-8f
#define AVAL (1.0f/2048.0f)   // a_i = 1/M = b_j = 1/N ; m = 1

typedef __bf16  bf16x8 __attribute__((ext_vector_type(8)));
typedef float   f32x4  __attribute__((ext_vector_type(4)));

__device__ __forceinline__ float wredsum(float x){
  #pragma unroll
  for (int off=32; off; off>>=1) x += __shfl_xor(x, off);
  return x;
}
__device__ __forceinline__ float wredmax(float x){
  #pragma unroll
  for (int off=32; off; off>>=1) x = fmaxf(x, __shfl_xor(x, off));
  return x;
}
__device__ __forceinline__ unsigned short f2bf(float x){
  unsigned int v = __float_as_uint(x);
  unsigned int r = (v + 0x7fffu + ((v>>16)&1u)) >> 16;   // RNE
  return (unsigned short)r;
}
__device__ __forceinline__ float bf2f(unsigned short u){ return __uint_as_float(((unsigned int)u)<<16); }
__device__ __forceinline__ float h2f(unsigned short h){
  _Float16 x; __builtin_memcpy(&x,&h,2); return (float)x;
}
__device__ __forceinline__ unsigned short f2h(float x){
  _Float16 h = (_Float16)x; unsigned short u; __builtin_memcpy(&u,&h,2); return u;
}

// ============ split-bf16 MFMA GEMM: S[b,m,n] fp32 = (1/16) * se^T te ============
// LDS granule layout per operand: [g in 0..3][m in 0..127] -> 16B granule of
// 8 consecutive k (bf16).  hi and lo planes separate.  Fragment read matches
// mfma_f32_16x16x32_bf16 A/B layout: lane m=l15(+tile), k = quad*8 + j.
__global__ __launch_bounds__(256) void gemm_kernel(const float* __restrict__ se,
                                                   const float* __restrict__ te,
                                                   float* __restrict__ S)
{
  __shared__ unsigned int Ah[2048], Al[2048], Bh[2048], Bl[2048];
  const int b  = blockIdx.z;
  const int mb = blockIdx.y;
  const int nb = blockIdx.x;
  const int t    = threadIdx.x;
  const int wave = t >> 6, lane = t & 63;
  const int wy = wave >> 1, wx = wave & 1;
  const int quad = lane >> 4, l15 = lane & 15;
  const int ml  = t & 127;          // staging: this thread's m (or n) column
  const int dh  = t >> 7;           // staging: which 16-d half of the 32-d chunk

  f32x4 acc[4][4] = {};

  const float* Abase = se + (size_t)b*D_*M_ + mb*128 + ml;
  const float* Bbase = te + (size_t)b*D_*M_ + nb*128 + ml;

  for (int kc=0; kc<8; kc++){
    __syncthreads();
    // ---- stage A ----
    {
      float x[16];
      #pragma unroll
      for (int j=0;j<16;j++) x[j] = Abase[(size_t)(kc*32 + dh*16 + j)*M_];
      #pragma unroll
      for (int gi=0; gi<2; gi++){
        unsigned int hw[4], lw[4];
        #pragma unroll
        for (int p=0;p<4;p++){
          float a0 = x[gi*8+2*p], a1 = x[gi*8+2*p+1];
          unsigned short h0 = f2bf(a0), h1 = f2bf(a1);
          unsigned short q0 = f2bf(a0 - bf2f(h0)), q1 = f2bf(a1 - bf2f(h1));
          hw[p] = (unsigned)h0 | ((unsigned)h1<<16);
          lw[p] = (unsigned)q0 | ((unsigned)q1<<16);
        }
        int idx = ((dh*2+gi)*128 + ml)*4;
        *(uint4*)&Ah[idx] = *(uint4*)hw;
        *(uint4*)&Al[idx] = *(uint4*)lw;
      }
    }
    // ---- stage B ----
    {
      float x[16];
      #pragma unroll
      for (int j=0;j<16;j++) x[j] = Bbase[(size_t)(kc*32 + dh*16 + j)*M_];
      #pragma unroll
      for (int gi=0; gi<2; gi++){
        unsigned int hw[4], lw[4];
        #pragma unroll
        for (int p=0;p<4;p++){
          float a0 = x[gi*8+2*p], a1 = x[gi*8+2*p+1];
          unsigned short h0 = f2bf(a0), h1 = f2bf(a1);
          unsigned short q0 = f2bf(a0 - bf2f(h0)), q1 = f2bf(a1 - bf2f(h1));
          hw[p] = (unsigned)h0 | ((unsigned)h1<<16);
          lw[p] = (unsigned)q0 | ((unsigned)q1<<16);
        }
        int idx = ((dh*2+gi)*128 + ml)*4;
        *(uint4*)&Bh[idx] = *(uint4*)hw;
        *(uint4*)&Bl[idx] = *(uint4*)lw;
      }
    }
    __syncthreads();
    bf16x8 ah[4], al[4], bh[4], bl[4];
    #pragma unroll
    for (int rt=0;rt<4;rt++){
      int ra = (quad*128 + wy*64 + rt*16 + l15)*4;
      int rb = (quad*128 + wx*64 + rt*16 + l15)*4;
      ah[rt] = *(const bf16x8*)&Ah[ra];
      al[rt] = *(const bf16x8*)&Al[ra];
      bh[rt] = *(const bf16x8*)&Bh[rb];
      bl[rt] = *(const bf16x8*)&Bl[rb];
    }
    #pragma unroll
    for (int rt=0;rt<4;rt++)
      #pragma unroll
      for (int ct=0;ct<4;ct++){
        acc[rt][ct] = __builtin_amdgcn_mfma_f32_16x16x32_bf16(ah[rt], bh[ct], acc[rt][ct], 0,0,0);
        acc[rt][ct] = __builtin_amdgcn_mfma_f32_16x16x32_bf16(ah[rt], bl[ct], acc[rt][ct], 0,0,0);
        acc[rt][ct] = __builtin_amdgcn_mfma_f32_16x16x32_bf16(al[rt], bh[ct], acc[rt][ct], 0,0,0);
      }
  }
  const float sc = 0.0625f;   // 1/sqrt(256)
  #pragma unroll
  for (int rt=0;rt<4;rt++){
    #pragma unroll
    for (int r=0;r<4;r++){
      int m = mb*128 + wy*64 + rt*16 + quad*4 + r;
      float* rowp = S + (size_t)(b*M_ + m)*N_;
      #pragma unroll
      for (int ct=0;ct<4;ct++){
        int n = nb*128 + wx*64 + ct*16 + l15;
        rowp[n] = acc[rt][ct][r] * sc;
      }
    }
  }
}

// ===== stats: per-row lse; K̂=exp((s-lse)/rho) stored fp16 in-place (front 4KB);
//       y0 = sum of the STORED fp16 K̂ (consistency with later passes) =====
__global__ __launch_bounds__(256) void stats_kernel(float* __restrict__ S,
                                                    const float* __restrict__ rho,
                                                    float* __restrict__ lse,
                                                    float* __restrict__ y0)
{
  const int b = blockIdx.y;
  const int m = blockIdx.x*4 + (threadIdx.x>>6);
  const int lane = threadIdx.x & 63;
  const float invrho = 1.0f / fmaxf(rho[0], EPSF);
  float* row = S + (size_t)(b*M_ + m)*N_;
  const float4* row4 = (const float4*)row;
  float4 vals[8];
  float mx = -3.4e38f;
  #pragma unroll
  for (int k=0;k<8;k++){
    float4 v = row4[lane + 64*k];
    vals[k] = v;
    mx = fmaxf(mx, fmaxf(fmaxf(v.x,v.y), fmaxf(v.z,v.w)));
  }
  mx = wredmax(mx);
  float e1=0.0f;
  #pragma unroll
  for (int k=0;k<8;k++){
    float4 v = vals[k];
    e1 += __expf(v.x-mx)+__expf(v.y-mx)+__expf(v.z-mx)+__expf(v.w-mx);
  }
  e1 = wredsum(e1);
  const float l = mx + __logf(e1);
  // all loads are consumed by the reductions above -> in-place stores are safe
  uint2* rowh2 = (uint2*)row;
  float y2 = 0.0f;
  #pragma unroll
  for (int k=0;k<8;k++){
    float4 v = vals[k];
    unsigned short h0 = f2h(__expf((v.x-l)*invrho));
    unsigned short h1 = f2h(__expf((v.y-l)*invrho));
    unsigned short h2 = f2h(__expf((v.z-l)*invrho));
    unsigned short h3 = f2h(__expf((v.w-l)*invrho));
    y2 += h2f(h0)+h2f(h1)+h2f(h2)+h2f(h3);
    uint2 pk;
    pk.x = (unsigned)h0 | ((unsigned)h1<<16);
    pk.y = (unsigned)h2 | ((unsigned)h3<<16);
    rowh2[lane + 64*k] = pk;
  }
  y2 = wredsum(y2);
  if (lane==0){
    lse[b*M_+m] = l;
    y0 [b*M_+m] = y2;
  }
}

__global__ __launch_bounds__(256) void init_kernel(const float* __restrict__ y0,
                                                   float* __restrict__ u, float* __restrict__ v,
                                                   float* __restrict__ w, float* __restrict__ g)
{
  const int b = blockIdx.x; const int t = threadIdx.x;
  float s = 0.0f;
  for (int i=t;i<M_;i+=256) s += y0[b*M_+i];
  s = wredsum(s);
  __shared__ float red[4];
  __shared__ float gsh;
  if ((t&63)==0) red[t>>6]=s;
  __syncthreads();
  if (t==0){
    float tot = red[0]+red[1]+red[2]+red[3];
    float gg = 1.0f / fmaxf(tot, EPSF);
    g[b]=gg; gsh=gg;
  }
  __syncthreads();
  float gg = gsh;
  for (int i=t;i<M_;i+=256){
    float rs = gg * y0[b*M_+i];
    u[b*M_+i] = fminf(AVAL / fmaxf(rs, EPSF), 1.0f);
    v[b*M_+i] = 1.0f;
    w[b*M_+i] = 0.0f;
  }
}

// ---- row pass: u_i *= min(a/max(g u_i (K̂ v)_i,eps),1); K̂ read as fp16, no exp ----
__global__ __launch_bounds__(256) void row_kernel(const float* __restrict__ S,
                                                  const float* __restrict__ vv,
                                                  float* __restrict__ u,
                                                  const float* __restrict__ g)
{
  const int b = blockIdx.y;
  const int m = blockIdx.x*4 + (threadIdx.x>>6);
  const int lane = threadIdx.x & 63;
  const uint4*  rowh = (const uint4*)(S + (size_t)(b*M_ + m)*N_);
  const float4* vp   = (const float4*)(vv + (size_t)b*N_);
  float acc=0.0f;
  #pragma unroll
  for (int k=0;k<4;k++){
    uint4 su = rowh[lane + 64*k];
    float4 v0 = vp[(lane+64*k)*2];
    float4 v1 = vp[(lane+64*k)*2+1];
    acc += h2f((unsigned short)(su.x&0xffff))*v0.x + h2f((unsigned short)(su.x>>16))*v0.y
         + h2f((unsigned short)(su.y&0xffff))*v0.z + h2f((unsigned short)(su.y>>16))*v0.w
         + h2f((unsigned short)(su.z&0xffff))*v1.x + h2f((unsigned short)(su.z>>16))*v1.y
         + h2f((unsigned short)(su.w&0xffff))*v1.z + h2f((unsigned short)(su.w>>16))*v1.w;
  }
  acc = wredsum(acc);
  if (lane==0){
    float ui = u[b*M_+m];
    float rs = g[b]*ui*acc;
    u[b*M_+m] = ui * fminf(AVAL / fmaxf(rs, EPSF), 1.0f);
  }
}

// ---- col pass: w_j += sum_i u_i K̂_ij over 64-row chunks ----
__global__ __launch_bounds__(256) void col_kernel(const float* __restrict__ S,
                                                  const float* __restrict__ u,
                                                  float* __restrict__ w)
{
  const int b  = blockIdx.y;
  const int i0 = blockIdx.x*64;
  const int t  = threadIdx.x;
  float acc[8];
  #pragma unroll
  for (int k=0;k<8;k++) acc[k]=0.0f;
  for (int i=0;i<64;i++){
    int r = i0+i;
    float ui = u[b*M_+r];
    uint4 su = ((const uint4*)(S + (size_t)(b*M_ + r)*N_))[t];
    acc[0] += ui*h2f((unsigned short)(su.x&0xffff));
    acc[1] += ui*h2f((unsigned short)(su.x>>16));
    acc[2] += ui*h2f((unsigned short)(su.y&0xffff));
    acc[3] += ui*h2f((unsigned short)(su.y>>16));
    acc[4] += ui*h2f((unsigned short)(su.z&0xffff));
    acc[5] += ui*h2f((unsigned short)(su.z>>16));
    acc[6] += ui*h2f((unsigned short)(su.w&0xffff));
    acc[7] += ui*h2f((unsigned short)(su.w>>16));
  }
  #pragma unroll
  for (int k=0;k<8;k++) atomicAdd(&w[b*N_+t*8+k], acc[k]);
}

__global__ __launch_bounds__(256) void vupd_kernel(float* __restrict__ w,
                                                   float* __restrict__ v,
                                                   float* __restrict__ g)
{
  const int b = blockIdx.x; const int t = threadIdx.x;
  const float gg = g[b];
  float part = 0.0f;
  for (int i=t;i<N_;i+=256){
    float wj = w[b*N_+i];
    float vj = v[b*N_+i];
    float c  = fminf(AVAL/fmaxf(gg*vj*wj,EPSF), 1.0f);
    vj *= c;
    v[b*N_+i]=vj;
    part += wj*vj;
    w[b*N_+i]=0.0f;
  }
  part = wredsum(part);
  __shared__ float red[4];
  if ((t&63)==0) red[t>>6]=part;
  __syncthreads();
  if (t==0){
    float tot = gg*(red[0]+red[1]+red[2]+red[3]);
    g[b] = gg / fmaxf(tot, EPSF);
  }
}

// ---- final: matches fp32 overwrite rows in place; fused rowsum + matches@t^T ----
__global__ __launch_bounds__(256) void final_kernel(float* __restrict__ S,
                                                    const float* __restrict__ u,
                                                    const float* __restrict__ v,
                                                    const float* __restrict__ g,
                                                    const float* __restrict__ tgt,
                                                    float* __restrict__ rowsum,
                                                    float* __restrict__ wref)
{
  const int b = blockIdx.y;
  const int m = blockIdx.x*4 + (threadIdx.x>>6);
  const int lane = threadIdx.x & 63;
  const float gu = g[b]*u[b*M_+m];
  float* row = S + (size_t)(b*M_ + m)*N_;
  const uint4* rowh = (const uint4*)row;
  uint4 su[4];
  #pragma unroll
  for (int k=0;k<4;k++) su[k] = rowh[lane + 64*k];
  // in-place overwrite below may clobber bytes other lanes are still loading:
  // drain all outstanding loads first.
  __builtin_amdgcn_s_waitcnt(0);
  float4* rowf = (float4*)row;
  const float4* vp = (const float4*)(v + (size_t)b*N_);
  const float4* t0 = (const float4*)(tgt + ((size_t)b*3+0)*N_);
  const float4* t1 = (const float4*)(tgt + ((size_t)b*3+1)*N_);
  const float4* t2 = (const float4*)(tgt + ((size_t)b*3+2)*N_);
  float rs=0.0f, a0=0.0f, a1=0.0f, a2=0.0f;
  #pragma unroll
  for (int k=0;k<4;k++){
    float s[8] = {h2f((unsigned short)(su[k].x&0xffff)), h2f((unsigned short)(su[k].x>>16)),
                  h2f((unsigned short)(su[k].y&0xffff)), h2f((unsigned short)(su[k].y>>16)),
                  h2f((unsigned short)(su[k].z&0xffff)), h2f((unsigned short)(su[k].z>>16)),
                  h2f((unsigned short)(su[k].w&0xffff)), h2f((unsigned short)(su[k].w>>16))};
    int i2 = (lane+64*k)*2;
    #pragma unroll
    for (int h=0;h<2;h++){
      float4 v4 = vp[i2+h];
      float4 q0 = t0[i2+h], q1 = t1[i2+h], q2 = t2[i2+h];
      float m0 = gu*s[h*4+0]*v4.x;
      float m1 = gu*s[h*4+1]*v4.y;
      float m2 = gu*s[h*4+2]*v4.z;
      float m3 = gu*s[h*4+3]*v4.w;
      rs += m0+m1+m2+m3;
      a0 += m0*q0.x + m1*q0.y + m2*q0.z + m3*q0.w;
      a1 += m0*q1.x + m1*q1.y + m2*q1.z + m3*q1.w;
      a2 += m0*q2.x + m1*q2.y + m2*q2.z + m3*q2.w;
      rowf[i2+h] = make_float4(m0,m1,m2,m3);
    }
  }
  rs = wredsum(rs); a0=wredsum(a0); a1=wredsum(a1); a2=wredsum(a2);
  if (lane==0){
    rowsum[b*M_+m] = rs;
    float inv = 1.0f/(rs+1e-6f);
    size_t o = ((size_t)b*M_+m)*3;
    wref[o]=a0*inv; wref[o+1]=a1*inv; wref[o+2]=a2*inv;
  }
}

// ---------------- 3x3 Kabsch via Jacobi on cov^T cov (verified R1) ----------------
__device__ __forceinline__ void mat3_svd_rot(const float cov[3][3], float R[3][3])
{
  float mx = 1e-30f;
  for (int p=0;p<3;p++) for (int q=0;q<3;q++) mx = fmaxf(mx, fabsf(cov[p][q]));
  const float inv = 1.0f/mx;
  float Cm[3][3];
  for (int p=0;p<3;p++) for (int q=0;q<3;q++) Cm[p][q]=cov[p][q]*inv;
  float G[3][3];
  for (int p=0;p<3;p++)
    for (int q=0;q<3;q++)
      G[p][q] = Cm[0][p]*Cm[0][q] + Cm[1][p]*Cm[1][q] + Cm[2][p]*Cm[2][q];
  float V[3][3] = {{1,0,0},{0,1,0},{0,0,1}};
  const int PP[3]={0,0,1}, QQ[3]={1,2,2};
  for (int sweep=0;sweep<12;sweep++){
    for (int r=0;r<3;r++){
      int p=PP[r], q=QQ[r];
      float apq = G[p][q];
      if (fabsf(apq) < 1e-20f) continue;
      float tau = (G[q][q]-G[p][p])/(2.0f*apq);
      float tt  = (tau>=0.0f?1.0f:-1.0f)/(fabsf(tau)+sqrtf(1.0f+tau*tau));
      float cc  = 1.0f/sqrtf(1.0f+tt*tt);
      float ss  = tt*cc;
      for (int k=0;k<3;k++){ float gkp=G[k][p], gkq=G[k][q]; G[k][p]=cc*gkp-ss*gkq; G[k][q]=ss*gkp+cc*gkq; }
      for (int k=0;k<3;k++){ float gpk=G[p][k], gqk=G[q][k]; G[p][k]=cc*gpk-ss*gqk; G[q][k]=ss*gpk+cc*gqk; }
      for (int k=0;k<3;k++){ float vkp=V[k][p], vkq=V[k][q]; V[k][p]=cc*vkp-ss*vkq; V[k][q]=ss*vkp+cc*vkq; }
    }
  }
  float ev[3]={G[0][0],G[1][1],G[2][2]};
  int i0=0,i1=1,i2=2,tmp;
  if (ev[i0]<ev[i1]){tmp=i0;i0=i1;i1=tmp;}
  if (ev[i0]<ev[i2]){tmp=i0;i0=i2;i2=tmp;}
  if (ev[i1]<ev[i2]){tmp=i1;i1=i2;i2=tmp;}
  const int idx[3]={i0,i1,i2};
  float Vs[3][3];
  for (int k=0;k<3;k++) for (int i=0;i<3;i++) Vs[i][k]=V[i][idx[k]];
  float U[3][3]; float nrm[3];
  for (int k=0;k<3;k++){
    float ux = Cm[0][0]*Vs[0][k]+Cm[0][1]*Vs[1][k]+Cm[0][2]*Vs[2][k];
    float uy = Cm[1][0]*Vs[0][k]+Cm[1][1]*Vs[1][k]+Cm[1][2]*Vs[2][k];
    float uz = Cm[2][0]*Vs[0][k]+Cm[2][1]*Vs[1][k]+Cm[2][2]*Vs[2][k];
    float n = sqrtf(ux*ux+uy*uy+uz*uz);
    nrm[k]=n;
    float in = (n>1e-20f)?1.0f/n:0.0f;
    U[0][k]=ux*in; U[1][k]=uy*in; U[2][k]=uz*in;
  }
  if (nrm[2] < 1e-6f*fmaxf(nrm[0],1e-20f)){
    U[0][2]=U[1][0]*U[2][1]-U[2][0]*U[1][1];
    U[1][2]=U[2][0]*U[0][1]-U[0][0]*U[2][1];
    U[2][2]=U[0][0]*U[1][1]-U[1][0]*U[0][1];
  }
  float detC = Cm[0][0]*(Cm[1][1]*Cm[2][2]-Cm[1][2]*Cm[2][1])
             - Cm[0][1]*(Cm[1][0]*Cm[2][2]-Cm[1][2]*Cm[2][0])
             + Cm[0][2]*(Cm[1][0]*Cm[2][1]-Cm[1][1]*Cm[2][0]);
  float d2 = (detC>0.0f)?1.0f:-1.0f;
  for (int p=0;p<3;p++)
    for (int q=0;q<3;q++)
      R[p][q] = Vs[p][0]*U[q][0] + Vs[p][1]*U[q][1] + d2*Vs[p][2]*U[q][2];
}

__global__ __launch_bounds__(256) void rigid_kernel(const float* __restrict__ src,
                                                    const float* __restrict__ wref,
                                                    const float* __restrict__ rowsum,
                                                    float* __restrict__ out)
{
  const int b = blockIdx.x; const int t = threadIdx.x;
  float acc[16];
  #pragma unroll
  for (int k=0;k<16;k++) acc[k]=0.0f;
  for (int i=t;i<M_;i+=256){
    float wgt = rowsum[b*M_+i];
    float ax = src[((size_t)b*3+0)*M_+i];
    float ay = src[((size_t)b*3+1)*M_+i];
    float az = src[((size_t)b*3+2)*M_+i];
    const float* wr = wref + ((size_t)b*M_+i)*3;
    float bx=wr[0], by=wr[1], bz=wr[2];
    acc[0]+=wgt;
    acc[1]+=wgt*ax; acc[2]+=wgt*ay; acc[3]+=wgt*az;
    acc[4]+=wgt*bx; acc[5]+=wgt*by; acc[6]+=wgt*bz;
    acc[7] +=wgt*ax*bx; acc[8] +=wgt*ax*by; acc[9] +=wgt*ax*bz;
    acc[10]+=wgt*ay*bx; acc[11]+=wgt*ay*by; acc[12]+=wgt*ay*bz;
    acc[13]+=wgt*az*bx; acc[14]+=wgt*az*by; acc[15]+=wgt*az*bz;
  }
  __shared__ float red[4][16];
  const int wid = t>>6, lane = t&63;
  #pragma unroll
  for (int k=0;k<16;k++){
    float v = acc[k];
    #pragma unroll
    for (int off=32; off; off>>=1) v += __shfl_xor(v, off);
    if (lane==0) red[wid][k]=v;
  }
  __syncthreads();
  if (t==0){
    float s[16];
    #pragma unroll
    for (int k=0;k<16;k++) s[k]=red[0][k]+red[1][k]+red[2][k]+red[3][k];
    float wsum = s[0];
    float denom = wsum + 1e-6f;
    float ca[3]={s[1]/denom, s[2]/denom, s[3]/denom};
    float cb[3]={s[4]/denom, s[5]/denom, s[6]/denom};
    float sw = wsum/denom;
    float cov[3][3];
    for (int p=0;p<3;p++)
      for (int q=0;q<3;q++)
        cov[p][q] = s[7+p*3+q]/denom + (sw-2.0f)*ca[p]*cb[q];
    float R[3][3];
    mat3_svd_rot(cov, R);
    float tr[3];
    for (int p=0;p<3;p++)
      tr[p] = -(R[p][0]*ca[0]+R[p][1]*ca[1]+R[p][2]*ca[2]) + cb[p];
    for (int p=0;p<3;p++)
      for (int q=0;q<3;q++)
        out[b*9 + p*3 + q] = R[p][q];
    for (int p=0;p<3;p++)
      out[144 + b*3 + p] = tr[p];
  }
}

extern "C" void kernel_launch(void* const* d_in, const int* in_sizes, int n_in,
                              void* d_out, int out_size, void* d_ws, size_t ws_size,
                              hipStream_t stream)
{
  const float* se  = (const float*)d_in[0];
  const float* te  = (const float*)d_in[1];
  const float* src = (const float*)d_in[2];
  const float* tgt = (const float*)d_in[3];
  const float* rho = (const float*)d_in[4];
  float* out = (float*)d_out;
  float* S   = out + 192;                 // matches region doubles as S / K̂ scratch
  float* ws  = (float*)d_ws;
  float* lse = ws;                        // 16*2048
  float* y0  = ws + 32768;                // 16*2048 (also final rowsum)
  float* u   = ws + 65536;
  float* v   = ws + 98304;
  float* w   = ws + 131072;
  float* g   = ws + 163840;               // 16
  float* wref= ws + 163904;               // 16*2048*3

  gemm_kernel <<<dim3(16,16,16),256,0,stream>>>(se,te,S);
  stats_kernel<<<dim3(512,16),  256,0,stream>>>(S,rho,lse,y0);
  init_kernel <<<dim3(16),      256,0,stream>>>(y0,u,v,w,g);
  for (int it=0; it<5; ++it){
    if (it>0) row_kernel<<<dim3(512,16),256,0,stream>>>(S,v,u,g);
    col_kernel <<<dim3(32,16),256,0,stream>>>(S,u,w);
    vupd_kernel<<<dim3(16),   256,0,stream>>>(w,v,g);
  }
  final_kernel<<<dim3(512,16),256,0,stream>>>(S,u,v,g,tgt,y0,wref);
  rigid_kernel<<<dim3(16),    256,0,stream>>>(src,wref,y0,out);
}